// Round 3
// baseline (732.270 us; speedup 1.0000x reference)
//
#include <hip/hip_runtime.h>
#include <hip/hip_bf16.h>

typedef __bf16 bf16;
typedef __bf16 bf16x4 __attribute__((ext_vector_type(4)));
typedef __bf16 bf16x8 __attribute__((ext_vector_type(8)));
typedef float  f32x4  __attribute__((ext_vector_type(4)));

#define AS1 __attribute__((address_space(1)))
#define AS3 __attribute__((address_space(3)))

__device__ __forceinline__ void gld_lds16(const void* g, void* l) {
    // async global->LDS, 16B per lane; LDS dest = wave-uniform base + lane*16
    __builtin_amdgcn_global_load_lds((AS1 void*)g, (AS3 void*)l, 16, 0, 0);
}

// ---------------------------------------------------------------------------
// bias[h][i][j] = table[rel_index[i*64+j]][h]   (all fp32)
// ---------------------------------------------------------------------------
__global__ void bias_kernel(const int* __restrict__ rel_index,
                            const float* __restrict__ table,
                            float* __restrict__ bias) {
    int idx = blockIdx.x * 256 + threadIdx.x;   // 0..65535 = h*4096 + rc
    int rc = idx & 4095;
    int h  = idx >> 12;
    bias[idx] = table[rel_index[rc] * 16 + h];
}

// ---------------------------------------------------------------------------
// GEMM1: C[m,n] = sum_k A[m,k]*B[n,k] + bias[n], A,B fp32; C written as bf16
// split into Cq (cols 0..511, stride 512) and Ckv (cols 512..1535, stride 1024).
// M=65536, N=1536, K=512, lda=512. 128x128 tile, BK=64, 256 thr.
// ---------------------------------------------------------------------------
__global__ __launch_bounds__(256) void gemm1_qkv(
    const float* __restrict__ A, const float* __restrict__ B,
    const float* __restrict__ bias, bf16* __restrict__ Cq,
    bf16* __restrict__ Ckv)
{
    __shared__ __attribute__((aligned(16))) bf16 As[128 * 64];
    __shared__ __attribute__((aligned(16))) bf16 Bs[128 * 64];
    const int K = 512, lda = 512;

    const int t    = threadIdx.x;
    const int w    = t >> 6;
    const int lane = t & 63;
    const int q    = lane >> 4;
    const int r16  = lane & 15;
    const int wm   = (w & 1) * 64;
    const int wn   = (w >> 1) * 64;
    const long bM  = (long)blockIdx.x * 128;
    const long bN  = (long)blockIdx.y * 128;

    f32x4 acc[4][4];
#pragma unroll
    for (int i = 0; i < 4; ++i)
#pragma unroll
        for (int j = 0; j < 4; ++j)
            acc[i][j] = f32x4{0.f, 0.f, 0.f, 0.f};

    for (int k0 = 0; k0 < K; k0 += 64) {
        // stage A,B: 128x64 fp32 -> bf16 LDS (8 float4 per thread per matrix)
#pragma unroll
        for (int i = 0; i < 8; ++i) {
            const int off = (i * 256 + t) * 4;      // 0..8191
            const int row = off >> 6, col = off & 63;
            f32x4 va = *(const f32x4*)(A + (bM + row) * (long)lda + k0 + col);
            f32x4 vb = *(const f32x4*)(B + (bN + row) * (long)K   + k0 + col);
            bf16x4 ha, hb;
#pragma unroll
            for (int e = 0; e < 4; ++e) { ha[e] = (bf16)va[e]; hb[e] = (bf16)vb[e]; }
            *(bf16x4*)&As[row * 64 + col] = ha;
            *(bf16x4*)&Bs[row * 64 + col] = hb;
        }
        __syncthreads();

#pragma unroll
        for (int ks = 0; ks < 2; ++ks) {
            bf16x8 av[4], bv[4];
#pragma unroll
            for (int i = 0; i < 4; ++i)
                av[i] = *(const bf16x8*)&As[(wm + i * 16 + r16) * 64 + ks * 32 + q * 8];
#pragma unroll
            for (int j = 0; j < 4; ++j)
                bv[j] = *(const bf16x8*)&Bs[(wn + j * 16 + r16) * 64 + ks * 32 + q * 8];
#pragma unroll
            for (int i = 0; i < 4; ++i)
#pragma unroll
                for (int j = 0; j < 4; ++j)
                    acc[i][j] = __builtin_amdgcn_mfma_f32_16x16x32_bf16(
                        av[i], bv[j], acc[i][j], 0, 0, 0);
        }
        __syncthreads();
    }

    // epilogue: C/D layout col=lane&15, row=quad*4+r ; split q | kv
    const bool isQ = (bN < 512);            // block-uniform (128 | 512)
#pragma unroll
    for (int j = 0; j < 4; ++j) {
        const long colg = bN + wn + j * 16 + r16;
        const float bvv = bias[colg];
#pragma unroll
        for (int i = 0; i < 4; ++i) {
            const long row = bM + wm + i * 16 + q * 4;
#pragma unroll
            for (int r = 0; r < 4; ++r) {
                const float v = acc[i][j][r] + bvv;
                if (isQ) Cq [(row + r) * 512  + colg]         = (bf16)v;
                else     Ckv[(row + r) * 1024 + (colg - 512)] = (bf16)v;
            }
        }
    }
}

// ---------------------------------------------------------------------------
// GEMM2 (proj): C[m,n] = sum_k A[m,k]*B[n,k] + bias[n]
// A bf16 (attn out, stride 512), B fp32 (proj_w), C fp32. M=65536,N=512,K=512.
// ---------------------------------------------------------------------------
__global__ __launch_bounds__(256) void gemm2_proj(
    const bf16* __restrict__ A, const float* __restrict__ B,
    const float* __restrict__ bias, float* __restrict__ C)
{
    __shared__ __attribute__((aligned(16))) bf16 As[128 * 64];
    __shared__ __attribute__((aligned(16))) bf16 Bs[128 * 64];
    const int K = 512;

    const int t    = threadIdx.x;
    const int w    = t >> 6;
    const int lane = t & 63;
    const int q    = lane >> 4;
    const int r16  = lane & 15;
    const int wm   = (w & 1) * 64;
    const int wn   = (w >> 1) * 64;
    const long bM  = (long)blockIdx.x * 128;
    const long bN  = (long)blockIdx.y * 128;

    const int sRow = lane >> 3;        // A async staging: 8 lanes per 64-el row
    const int sCol = (lane & 7) * 8;

    f32x4 acc[4][4];
#pragma unroll
    for (int i = 0; i < 4; ++i)
#pragma unroll
        for (int j = 0; j < 4; ++j)
            acc[i][j] = f32x4{0.f, 0.f, 0.f, 0.f};

    for (int k0 = 0; k0 < K; k0 += 64) {
        // A: async bf16 16B/lane
#pragma unroll
        for (int it = 0; it < 4; ++it) {
            const int chunk = w * 4 + it;
            const int row   = chunk * 8 + sRow;
            gld_lds16(A + (bM + row) * 512L + k0 + sCol, As + chunk * 512);
        }
        // B: fp32 -> bf16 via registers
#pragma unroll
        for (int i = 0; i < 8; ++i) {
            const int off = (i * 256 + t) * 4;
            const int row = off >> 6, col = off & 63;
            f32x4 vb = *(const f32x4*)(B + (bN + row) * (long)K + k0 + col);
            bf16x4 hb;
#pragma unroll
            for (int e = 0; e < 4; ++e) hb[e] = (bf16)vb[e];
            *(bf16x4*)&Bs[row * 64 + col] = hb;
        }
        asm volatile("s_waitcnt vmcnt(0)" ::: "memory");
        __syncthreads();

#pragma unroll
        for (int ks = 0; ks < 2; ++ks) {
            bf16x8 av[4], bv[4];
#pragma unroll
            for (int i = 0; i < 4; ++i)
                av[i] = *(const bf16x8*)&As[(wm + i * 16 + r16) * 64 + ks * 32 + q * 8];
#pragma unroll
            for (int j = 0; j < 4; ++j)
                bv[j] = *(const bf16x8*)&Bs[(wn + j * 16 + r16) * 64 + ks * 32 + q * 8];
#pragma unroll
            for (int i = 0; i < 4; ++i)
#pragma unroll
                for (int j = 0; j < 4; ++j)
                    acc[i][j] = __builtin_amdgcn_mfma_f32_16x16x32_bf16(
                        av[i], bv[j], acc[i][j], 0, 0, 0);
        }
        __syncthreads();
    }

#pragma unroll
    for (int j = 0; j < 4; ++j) {
        const long col = bN + wn + j * 16 + r16;
        const float bvv = bias[col];
#pragma unroll
        for (int i = 0; i < 4; ++i) {
            const long row = bM + wm + i * 16 + q * 4;
#pragma unroll
            for (int r = 0; r < 4; ++r)
                C[(row + r) * 512L + col] = acc[i][j][r] + bvv;
        }
    }
}

// ---------------------------------------------------------------------------
// Window attention: one wave per (window bw, head h).
// qbuf: (65536,512) bf16 = q; kv: (65536,1024) bf16 = [k | v].
// Output written IN PLACE into qbuf cols h*32..h*32+31 (disjoint from every
// other block's reads; k/v never written).
// ---------------------------------------------------------------------------
__global__ __launch_bounds__(64) void attn_kernel(
    bf16* __restrict__ qbuf, const bf16* __restrict__ kv,
    const float* __restrict__ mask, const float* __restrict__ bias)
{
    __shared__ __attribute__((aligned(16))) bf16 smem[6144];  // 12 KB
    bf16* Qs = smem;          // [64][32]
    bf16* Ks = smem + 2048;   // [64][32]
    bf16* Vt = smem + 4096;   // [32][64]
    bf16* Ps = smem;          // [64][64] reuses Qs+Ks

    const int lane = threadIdx.x;
    const int q    = lane >> 4;
    const int r16  = lane & 15;
    const int bw   = blockIdx.x >> 4;
    const int h    = blockIdx.x & 15;
    const int nw   = bw & 63;
    const long rowbase = (long)bw * 64;

#pragma unroll
    for (int it = 0; it < 4; ++it) {
        const int tok  = it * 16 + (lane >> 2);
        const int part = (lane & 3) * 8;
        gld_lds16(qbuf + (rowbase + tok) * 512  + h * 32 + part, Qs + it * 512);
        gld_lds16(kv   + (rowbase + tok) * 1024 + h * 32 + part, Ks + it * 512);
    }
    {
        const bf16* gv = kv + (rowbase + lane) * 1024 + 512 + h * 32;
        uint4 vtmp[4];
#pragma unroll
        for (int jj = 0; jj < 4; ++jj) vtmp[jj] = ((const uint4*)gv)[jj];
        const bf16* vrow = (const bf16*)vtmp;
#pragma unroll
        for (int hd = 0; hd < 32; ++hd)
            Vt[hd * 64 + lane] = vrow[hd];
    }
    asm volatile("s_waitcnt vmcnt(0)" ::: "memory");
    __syncthreads();

    f32x4 acc[4][4];
    {
        bf16x8 av[4], bv[4];
#pragma unroll
        for (int ti = 0; ti < 4; ++ti)
            av[ti] = *(const bf16x8*)&Qs[(ti * 16 + r16) * 32 + q * 8];
#pragma unroll
        for (int tj = 0; tj < 4; ++tj)
            bv[tj] = *(const bf16x8*)&Ks[(tj * 16 + r16) * 32 + q * 8];
        const f32x4 z = f32x4{0.f, 0.f, 0.f, 0.f};
#pragma unroll
        for (int ti = 0; ti < 4; ++ti)
#pragma unroll
            for (int tj = 0; tj < 4; ++tj)
                acc[ti][tj] = __builtin_amdgcn_mfma_f32_16x16x32_bf16(
                    av[ti], bv[tj], z, 0, 0, 0);
    }

    const float SCALE  = 0.17677669529663687f;   // 1/sqrt(32)
    const float LOG2E  = 1.4426950408889634f;
    const float* biasH = bias + h * 4096;
    const float* maskW = mask + nw * 4096;

#pragma unroll
    for (int ti = 0; ti < 4; ++ti) {
#pragma unroll
        for (int r = 0; r < 4; ++r) {
            const int row = ti * 16 + q * 4 + r;
            float mx = -1e30f;
#pragma unroll
            for (int tj = 0; tj < 4; ++tj) {
                const int col = tj * 16 + r16;
                float s = acc[ti][tj][r] * SCALE
                        + biasH[row * 64 + col] + maskW[row * 64 + col];
                acc[ti][tj][r] = s;
                mx = fmaxf(mx, s);
            }
#pragma unroll
            for (int d = 1; d < 16; d <<= 1)
                mx = fmaxf(mx, __shfl_xor(mx, d, 16));
            float sum = 0.f;
#pragma unroll
            for (int tj = 0; tj < 4; ++tj) {
                float e = exp2f((acc[ti][tj][r] - mx) * LOG2E);
                acc[ti][tj][r] = e;
                sum += e;
            }
#pragma unroll
            for (int d = 1; d < 16; d <<= 1)
                sum += __shfl_xor(sum, d, 16);
            const float inv = 1.0f / sum;
#pragma unroll
            for (int tj = 0; tj < 4; ++tj)
                Ps[row * 64 + tj * 16 + r16] = (bf16)(acc[ti][tj][r] * inv);
        }
    }
    __syncthreads();

    f32x4 o[4][2];
#pragma unroll
    for (int ti = 0; ti < 4; ++ti)
#pragma unroll
        for (int tn = 0; tn < 2; ++tn)
            o[ti][tn] = f32x4{0.f, 0.f, 0.f, 0.f};

#pragma unroll
    for (int ks = 0; ks < 2; ++ks) {
        bf16x8 av[4], bv[2];
#pragma unroll
        for (int ti = 0; ti < 4; ++ti)
            av[ti] = *(const bf16x8*)&Ps[(ti * 16 + r16) * 64 + ks * 32 + q * 8];
#pragma unroll
        for (int tn = 0; tn < 2; ++tn)
            bv[tn] = *(const bf16x8*)&Vt[(tn * 16 + r16) * 64 + ks * 32 + q * 8];
#pragma unroll
        for (int ti = 0; ti < 4; ++ti)
#pragma unroll
            for (int tn = 0; tn < 2; ++tn)
                o[ti][tn] = __builtin_amdgcn_mfma_f32_16x16x32_bf16(
                    av[ti], bv[tn], o[ti][tn], 0, 0, 0);
    }

    bf16* op = qbuf + rowbase * 512 + h * 32;
#pragma unroll
    for (int ti = 0; ti < 4; ++ti)
#pragma unroll
        for (int tn = 0; tn < 2; ++tn)
#pragma unroll
            for (int r = 0; r < 4; ++r)
                op[(long)(ti * 16 + q * 4 + r) * 512 + tn * 16 + r16] =
                    (bf16)(o[ti][tn][r]);
}

// ---------------------------------------------------------------------------
extern "C" void kernel_launch(void* const* d_in, const int* in_sizes, int n_in,
                              void* d_out, int out_size, void* d_ws, size_t ws_size,
                              hipStream_t stream) {
    const float* x      = (const float*)d_in[0];
    const float* mask   = (const float*)d_in[1];
    const float* qkv_w  = (const float*)d_in[2];
    const float* qkv_b  = (const float*)d_in[3];
    const float* table  = (const float*)d_in[4];
    const float* proj_w = (const float*)d_in[5];
    const float* proj_b = (const float*)d_in[6];
    const int*   relidx = (const int*)d_in[7];
    float* out = (float*)d_out;

    char*  ws    = (char*)d_ws;
    float* bias  = (float*)ws;                    // 256 KB
    bf16*  qbuf  = (bf16*)(ws + 262144);          // 67.1 MB (q, then attn out)
    const size_t need_full = 262144ull + 67108864ull + 134217728ull; // 201.6 MB
    // kv scratch: in ws if it fits, else in d_out (134.2 MB fp32; dead before
    // gemm2 overwrites it with the final output)
    bf16* kvbuf = (ws_size >= need_full) ? (bf16*)(ws + 262144 + 67108864)
                                         : (bf16*)d_out;

    bias_kernel<<<256, 256, 0, stream>>>(relidx, table, bias);
    gemm1_qkv<<<dim3(512, 12), 256, 0, stream>>>(x, qkv_w, qkv_b, qbuf, kvbuf);
    attn_kernel<<<16384, 64, 0, stream>>>(qbuf, kvbuf, mask, bias);
    gemm2_proj<<<dim3(512, 4), 256, 0, stream>>>(qbuf, proj_w, proj_b, out);
}

// Round 4
// 615.773 us; speedup vs baseline: 1.1892x; 1.1892x over previous
//
#include <hip/hip_runtime.h>
#include <hip/hip_bf16.h>

typedef __bf16 bf16;
typedef __bf16 bf16x4 __attribute__((ext_vector_type(4)));
typedef __bf16 bf16x8 __attribute__((ext_vector_type(8)));
typedef float  f32x4  __attribute__((ext_vector_type(4)));

#define AS1 __attribute__((address_space(1)))
#define AS3 __attribute__((address_space(3)))

__device__ __forceinline__ void gld_lds16(const void* g, void* l) {
    // async global->LDS, 16B per lane; LDS dest = wave-uniform base + lane*16
    __builtin_amdgcn_global_load_lds((AS1 void*)g, (AS3 void*)l, 16, 0, 0);
}

// ---------------------------------------------------------------------------
// fp32 -> bf16 bulk convert, float4-vectorized grid-stride
// ---------------------------------------------------------------------------
__global__ void cvt_kernel(const float* __restrict__ in, bf16* __restrict__ out,
                           int n4) {
    for (long i = (long)blockIdx.x * blockDim.x + threadIdx.x; i < n4;
         i += (long)gridDim.x * blockDim.x) {
        f32x4 v = ((const f32x4*)in)[i];
        bf16x4 h;
#pragma unroll
        for (int e = 0; e < 4; ++e) h[e] = (bf16)v[e];
        ((bf16x4*)out)[i] = h;
    }
}

// ---------------------------------------------------------------------------
// bias[h][i][j] = table[rel_index[i*64+j]][h]   (all fp32)
// ---------------------------------------------------------------------------
__global__ void bias_kernel(const int* __restrict__ rel_index,
                            const float* __restrict__ table,
                            float* __restrict__ bias) {
    int idx = blockIdx.x * 256 + threadIdx.x;   // 0..65535 = h*4096 + rc
    int rc = idx & 4095;
    int h  = idx >> 12;
    bias[idx] = table[rel_index[rc] * 16 + h];
}

// ---------------------------------------------------------------------------
// GEMM1 (qkv): C[m,n] = sum_k A[m,k]*B[n,k] + bias[n], A,B bf16 (pre-converted)
// C split: q cols 0..511 -> Cq (stride 512), k/v cols 512..1535 -> Ckv (1024).
// M=65536, N=1536, K=512. 128x128 tile, BK=64, 256 thr, async staging (m97).
// ---------------------------------------------------------------------------
__global__ __launch_bounds__(256) void gemm1_qkv(
    const bf16* __restrict__ A, const bf16* __restrict__ B,
    const float* __restrict__ bias, bf16* __restrict__ Cq,
    bf16* __restrict__ Ckv)
{
    __shared__ __attribute__((aligned(16))) bf16 As[128 * 64];
    __shared__ __attribute__((aligned(16))) bf16 Bs[128 * 64];

    const int t    = threadIdx.x;
    const int w    = t >> 6;
    const int lane = t & 63;
    const int q    = lane >> 4;
    const int r16  = lane & 15;
    const int wm   = (w & 1) * 64;
    const int wn   = (w >> 1) * 64;
    const long bM  = (long)blockIdx.x * 128;
    const long bN  = (long)blockIdx.y * 128;

    const int sRow = lane >> 3;        // 8 lanes per 64-elem (128 B) row
    const int sCol = (lane & 7) * 8;

    f32x4 acc[4][4];
#pragma unroll
    for (int i = 0; i < 4; ++i)
#pragma unroll
        for (int j = 0; j < 4; ++j)
            acc[i][j] = f32x4{0.f, 0.f, 0.f, 0.f};

    for (int k0 = 0; k0 < 512; k0 += 64) {
#pragma unroll
        for (int it = 0; it < 4; ++it) {
            const int chunk = w * 4 + it;          // wave-uniform 0..15
            const int row   = chunk * 8 + sRow;
            gld_lds16(A + (bM + row) * 512L + k0 + sCol, As + chunk * 512);
            gld_lds16(B + (bN + row) * 512L + k0 + sCol, Bs + chunk * 512);
        }
        asm volatile("s_waitcnt vmcnt(0)" ::: "memory");
        __syncthreads();

#pragma unroll
        for (int ks = 0; ks < 2; ++ks) {
            bf16x8 av[4], bv[4];
#pragma unroll
            for (int i = 0; i < 4; ++i)
                av[i] = *(const bf16x8*)&As[(wm + i * 16 + r16) * 64 + ks * 32 + q * 8];
#pragma unroll
            for (int j = 0; j < 4; ++j)
                bv[j] = *(const bf16x8*)&Bs[(wn + j * 16 + r16) * 64 + ks * 32 + q * 8];
#pragma unroll
            for (int i = 0; i < 4; ++i)
#pragma unroll
                for (int j = 0; j < 4; ++j)
                    acc[i][j] = __builtin_amdgcn_mfma_f32_16x16x32_bf16(
                        av[i], bv[j], acc[i][j], 0, 0, 0);
        }
        __syncthreads();
    }

    // epilogue: C/D layout col=lane&15, row=quad*4+r ; split q | kv
    const bool isQ = (bN < 512);            // block-uniform
#pragma unroll
    for (int j = 0; j < 4; ++j) {
        const long colg = bN + wn + j * 16 + r16;
        const float bvv = bias[colg];
#pragma unroll
        for (int i = 0; i < 4; ++i) {
            const long row = bM + wm + i * 16 + q * 4;
#pragma unroll
            for (int r = 0; r < 4; ++r) {
                const float v = acc[i][j][r] + bvv;
                if (isQ) Cq [(row + r) * 512  + colg]         = (bf16)v;
                else     Ckv[(row + r) * 1024 + (colg - 512)] = (bf16)v;
            }
        }
    }
}

// ---------------------------------------------------------------------------
// GEMM2 (proj): C[m,n] = sum_k A[m,k]*B[n,k] + bias[n]
// A bf16 (attn out, stride 512), B bf16 (pre-converted proj_w), C fp32.
// M=65536, N=512, K=512.
// ---------------------------------------------------------------------------
__global__ __launch_bounds__(256) void gemm2_proj(
    const bf16* __restrict__ A, const bf16* __restrict__ B,
    const float* __restrict__ bias, float* __restrict__ C)
{
    __shared__ __attribute__((aligned(16))) bf16 As[128 * 64];
    __shared__ __attribute__((aligned(16))) bf16 Bs[128 * 64];

    const int t    = threadIdx.x;
    const int w    = t >> 6;
    const int lane = t & 63;
    const int q    = lane >> 4;
    const int r16  = lane & 15;
    const int wm   = (w & 1) * 64;
    const int wn   = (w >> 1) * 64;
    const long bM  = (long)blockIdx.x * 128;
    const long bN  = (long)blockIdx.y * 128;

    const int sRow = lane >> 3;
    const int sCol = (lane & 7) * 8;

    f32x4 acc[4][4];
#pragma unroll
    for (int i = 0; i < 4; ++i)
#pragma unroll
        for (int j = 0; j < 4; ++j)
            acc[i][j] = f32x4{0.f, 0.f, 0.f, 0.f};

    for (int k0 = 0; k0 < 512; k0 += 64) {
#pragma unroll
        for (int it = 0; it < 4; ++it) {
            const int chunk = w * 4 + it;
            const int row   = chunk * 8 + sRow;
            gld_lds16(A + (bM + row) * 512L + k0 + sCol, As + chunk * 512);
            gld_lds16(B + (bN + row) * 512L + k0 + sCol, Bs + chunk * 512);
        }
        asm volatile("s_waitcnt vmcnt(0)" ::: "memory");
        __syncthreads();

#pragma unroll
        for (int ks = 0; ks < 2; ++ks) {
            bf16x8 av[4], bv[4];
#pragma unroll
            for (int i = 0; i < 4; ++i)
                av[i] = *(const bf16x8*)&As[(wm + i * 16 + r16) * 64 + ks * 32 + q * 8];
#pragma unroll
            for (int j = 0; j < 4; ++j)
                bv[j] = *(const bf16x8*)&Bs[(wn + j * 16 + r16) * 64 + ks * 32 + q * 8];
#pragma unroll
            for (int i = 0; i < 4; ++i)
#pragma unroll
                for (int j = 0; j < 4; ++j)
                    acc[i][j] = __builtin_amdgcn_mfma_f32_16x16x32_bf16(
                        av[i], bv[j], acc[i][j], 0, 0, 0);
        }
        __syncthreads();
    }

#pragma unroll
    for (int j = 0; j < 4; ++j) {
        const long col = bN + wn + j * 16 + r16;
        const float bvv = bias[col];
#pragma unroll
        for (int i = 0; i < 4; ++i) {
            const long row = bM + wm + i * 16 + q * 4;
#pragma unroll
            for (int r = 0; r < 4; ++r)
                C[(row + r) * 512L + col] = acc[i][j][r] + bvv;
        }
    }
}

// ---------------------------------------------------------------------------
// Window attention: one wave per (window bw, head h).
// qbuf: (65536,512) bf16 = q; kv: (65536,1024) bf16 = [k | v].
// Output written IN PLACE into qbuf cols h*32..h*32+31.
// ---------------------------------------------------------------------------
__global__ __launch_bounds__(64) void attn_kernel(
    bf16* __restrict__ qbuf, const bf16* __restrict__ kv,
    const float* __restrict__ mask, const float* __restrict__ bias)
{
    __shared__ __attribute__((aligned(16))) bf16 smem[6144];  // 12 KB
    bf16* Qs = smem;          // [64][32]
    bf16* Ks = smem + 2048;   // [64][32]
    bf16* Vt = smem + 4096;   // [32][64]
    bf16* Ps = smem;          // [64][64] reuses Qs+Ks

    const int lane = threadIdx.x;
    const int q    = lane >> 4;
    const int r16  = lane & 15;
    const int bw   = blockIdx.x >> 4;
    const int h    = blockIdx.x & 15;
    const int nw   = bw & 63;
    const long rowbase = (long)bw * 64;

#pragma unroll
    for (int it = 0; it < 4; ++it) {
        const int tok  = it * 16 + (lane >> 2);
        const int part = (lane & 3) * 8;
        gld_lds16(qbuf + (rowbase + tok) * 512  + h * 32 + part, Qs + it * 512);
        gld_lds16(kv   + (rowbase + tok) * 1024 + h * 32 + part, Ks + it * 512);
    }
    {
        const bf16* gv = kv + (rowbase + lane) * 1024 + 512 + h * 32;
        uint4 vtmp[4];
#pragma unroll
        for (int jj = 0; jj < 4; ++jj) vtmp[jj] = ((const uint4*)gv)[jj];
        const bf16* vrow = (const bf16*)vtmp;
#pragma unroll
        for (int hd = 0; hd < 32; ++hd)
            Vt[hd * 64 + lane] = vrow[hd];
    }
    asm volatile("s_waitcnt vmcnt(0)" ::: "memory");
    __syncthreads();

    f32x4 acc[4][4];
    {
        bf16x8 av[4], bv[4];
#pragma unroll
        for (int ti = 0; ti < 4; ++ti)
            av[ti] = *(const bf16x8*)&Qs[(ti * 16 + r16) * 32 + q * 8];
#pragma unroll
        for (int tj = 0; tj < 4; ++tj)
            bv[tj] = *(const bf16x8*)&Ks[(tj * 16 + r16) * 32 + q * 8];
        const f32x4 z = f32x4{0.f, 0.f, 0.f, 0.f};
#pragma unroll
        for (int ti = 0; ti < 4; ++ti)
#pragma unroll
            for (int tj = 0; tj < 4; ++tj)
                acc[ti][tj] = __builtin_amdgcn_mfma_f32_16x16x32_bf16(
                    av[ti], bv[tj], z, 0, 0, 0);
    }

    const float SCALE  = 0.17677669529663687f;   // 1/sqrt(32)
    const float LOG2E  = 1.4426950408889634f;
    const float* biasH = bias + h * 4096;
    const float* maskW = mask + nw * 4096;

#pragma unroll
    for (int ti = 0; ti < 4; ++ti) {
#pragma unroll
        for (int r = 0; r < 4; ++r) {
            const int row = ti * 16 + q * 4 + r;
            float mx = -1e30f;
#pragma unroll
            for (int tj = 0; tj < 4; ++tj) {
                const int col = tj * 16 + r16;
                float s = acc[ti][tj][r] * SCALE
                        + biasH[row * 64 + col] + maskW[row * 64 + col];
                acc[ti][tj][r] = s;
                mx = fmaxf(mx, s);
            }
#pragma unroll
            for (int d = 1; d < 16; d <<= 1)
                mx = fmaxf(mx, __shfl_xor(mx, d, 16));
            float sum = 0.f;
#pragma unroll
            for (int tj = 0; tj < 4; ++tj) {
                float e = exp2f((acc[ti][tj][r] - mx) * LOG2E);
                acc[ti][tj][r] = e;
                sum += e;
            }
#pragma unroll
            for (int d = 1; d < 16; d <<= 1)
                sum += __shfl_xor(sum, d, 16);
            const float inv = 1.0f / sum;
#pragma unroll
            for (int tj = 0; tj < 4; ++tj)
                Ps[row * 64 + tj * 16 + r16] = (bf16)(acc[ti][tj][r] * inv);
        }
    }
    __syncthreads();

    f32x4 o[4][2];
#pragma unroll
    for (int ti = 0; ti < 4; ++ti)
#pragma unroll
        for (int tn = 0; tn < 2; ++tn)
            o[ti][tn] = f32x4{0.f, 0.f, 0.f, 0.f};

#pragma unroll
    for (int ks = 0; ks < 2; ++ks) {
        bf16x8 av[4], bv[2];
#pragma unroll
        for (int ti = 0; ti < 4; ++ti)
            av[ti] = *(const bf16x8*)&Ps[(ti * 16 + r16) * 64 + ks * 32 + q * 8];
#pragma unroll
        for (int tn = 0; tn < 2; ++tn)
            bv[tn] = *(const bf16x8*)&Vt[(tn * 16 + r16) * 64 + ks * 32 + q * 8];
#pragma unroll
        for (int ti = 0; ti < 4; ++ti)
#pragma unroll
            for (int tn = 0; tn < 2; ++tn)
                o[ti][tn] = __builtin_amdgcn_mfma_f32_16x16x32_bf16(
                    av[ti], bv[tn], o[ti][tn], 0, 0, 0);
    }

    bf16* op = qbuf + rowbase * 512 + h * 32;
#pragma unroll
    for (int ti = 0; ti < 4; ++ti)
#pragma unroll
        for (int tn = 0; tn < 2; ++tn)
#pragma unroll
            for (int r = 0; r < 4; ++r)
                op[(long)(ti * 16 + q * 4 + r) * 512 + tn * 16 + r16] =
                    (bf16)(o[ti][tn][r]);
}

// ---------------------------------------------------------------------------
extern "C" void kernel_launch(void* const* d_in, const int* in_sizes, int n_in,
                              void* d_out, int out_size, void* d_ws, size_t ws_size,
                              hipStream_t stream) {
    const float* x      = (const float*)d_in[0];
    const float* mask   = (const float*)d_in[1];
    const float* qkv_w  = (const float*)d_in[2];
    const float* qkv_b  = (const float*)d_in[3];
    const float* table  = (const float*)d_in[4];
    const float* proj_w = (const float*)d_in[5];
    const float* proj_b = (const float*)d_in[6];
    const int*   relidx = (const int*)d_in[7];
    float* out = (float*)d_out;

    // ws layout (bytes):
    //   bias  @ 0          256 KB   fp32 (NH,64,64)
    //   qbuf  @ 262144     67.1 MB  bf16 q, then attn-out in place
    //   xbf   @ 67371008   67.1 MB  bf16 x
    //   wq    @ 134479872  1.57 MB  bf16 qkv_w
    //   wp    @ 136052736  0.52 MB  bf16 proj_w
    //   kv    @ 136577024  134.2 MB bf16 [k|v]  (or aliased to d_out if ws small)
    char*  ws   = (char*)d_ws;
    float* bias = (float*)ws;
    bf16*  qbuf = (bf16*)(ws + 262144);
    bf16*  xbf  = (bf16*)(ws + 67371008);
    bf16*  wq   = (bf16*)(ws + 134479872);
    bf16*  wp   = (bf16*)(ws + 136052736);
    const size_t need_full = 136577024ull + 134217728ull;  // 270.8 MB
    // kv scratch: d_out is 134.2 MB fp32 and dead until gemm2 overwrites it
    bf16* kvbuf = (ws_size >= need_full) ? (bf16*)(ws + 136577024)
                                         : (bf16*)d_out;

    bias_kernel<<<256, 256, 0, stream>>>(relidx, table, bias);
    cvt_kernel<<<2048, 256, 0, stream>>>(x,      xbf, 8388608);  // 33.5M elems
    cvt_kernel<<<768,  256, 0, stream>>>(qkv_w,  wq,  196608);
    cvt_kernel<<<256,  256, 0, stream>>>(proj_w, wp,  65536);

    gemm1_qkv<<<dim3(512, 12), 256, 0, stream>>>(xbf, wq, qkv_b, qbuf, kvbuf);
    attn_kernel<<<16384, 64, 0, stream>>>(qbuf, kvbuf, mask, bias);
    gemm2_proj<<<dim3(512, 4), 256, 0, stream>>>(qbuf, wp, proj_b, out);
}